// Round 1
// baseline (111.793 us; speedup 1.0000x reference)
//
#include <hip/hip_runtime.h>

// S4D diagonal SSM kernel generation (ZOH, real_type='exp', B=general, rep=1)
// K[h,l] = 2*Re( sum_n Cd[h,n] * w[h,n]^l ),  w = exp(dt*A),
// Cd = B*C * (w-1)/A.
//
// Structure: one block per h. Setup phase (lanes 0..63) computes per-n
// coefficients + power table w^(16*2^k) into LDS. Main phase: each of 128
// threads owns 16 consecutive l; init u = Cd*w^(16t) via bit-product
// (branch-free cndmask), then a 16-step complex-multiply recurrence.
// No transcendentals in the hot loop; all LDS reads are wave-uniform
// broadcasts (conflict-free).

#define H_DIM 768
#define N_DIM 64
#define L_DIM 2048
#define LCH   16
#define TPB   128  // L_DIM / LCH

__global__ __launch_bounds__(TPB) void s4d_gen_kernel(
    const float* __restrict__ log_dt,
    const float* __restrict__ B_ri,
    const float* __restrict__ inv_A_real,
    const float* __restrict__ A_imag,
    const float* __restrict__ C_ri,
    float* __restrict__ out)
{
    __shared__ float sGr[N_DIM], sGi[N_DIM];      // 2*Cd
    __shared__ float sWr[N_DIM], sWi[N_DIM];      // w
    __shared__ float sTr[7][N_DIM], sTi[7][N_DIM]; // w^(16*2^k), k=0..6

    const int h = blockIdx.x;
    const int t = threadIdx.x;

    if (t < N_DIM) {
        const int n   = t;
        const int idx = h * N_DIM + n;
        const float dt   = expf(log_dt[h]);
        const float Ar   = -expf(inv_A_real[idx]);
        const float Ai   = A_imag[idx];
        const float dtAr = Ar * dt;
        const float dtAi = Ai * dt;
        // w = exp(dtA)
        const float e = expf(dtAr);
        float s, c;
        sincosf(dtAi, &s, &c);
        const float wr = e * c, wi = e * s;
        // q = (w - 1) / A  via conj(A)/|A|^2   (Ar != 0 always: -exp(x))
        const float inv = 1.0f / (Ar * Ar + Ai * Ai);
        const float nr = wr - 1.0f, ni = wi;
        const float qr = (nr * Ar + ni * Ai) * inv;
        const float qi = (ni * Ar - nr * Ai) * inv;
        // B*C
        const float Br = B_ri[2 * idx], Bi = B_ri[2 * idx + 1];
        const float Cr = C_ri[2 * idx], Ci = C_ri[2 * idx + 1];
        const float BCr = Br * Cr - Bi * Ci;
        const float BCi = Br * Ci + Bi * Cr;
        // G = 2 * (B*C) * q
        sGr[n] = 2.0f * (BCr * qr - BCi * qi);
        sGi[n] = 2.0f * (BCr * qi + BCi * qr);
        sWr[n] = wr;
        sWi[n] = wi;
        // power table: p = w^16, then store p and square 7 times
        float pr = wr, pi = wi;
        #pragma unroll
        for (int k = 0; k < 4; ++k) { float t2 = pr*pr - pi*pi; pi = 2.0f*pr*pi; pr = t2; }
        #pragma unroll
        for (int k = 0; k < 7; ++k) {
            sTr[k][n] = pr; sTi[k][n] = pi;
            float t2 = pr*pr - pi*pi; pi = 2.0f*pr*pi; pr = t2;
        }
    }
    __syncthreads();

    float acc[LCH];
    #pragma unroll
    for (int j = 0; j < LCH; ++j) acc[j] = 0.0f;

    for (int n = 0; n < N_DIM; n += 2) {
        // init u = G * w^(16*t) via bits of t (branch-free)
        float u0r = sGr[n],     u0i = sGi[n];
        float u1r = sGr[n + 1], u1i = sGi[n + 1];
        #pragma unroll
        for (int k = 0; k < 7; ++k) {
            const bool b = (t >> k) & 1;
            const float m0r = b ? sTr[k][n]     : 1.0f;
            const float m0i = b ? sTi[k][n]     : 0.0f;
            const float m1r = b ? sTr[k][n + 1] : 1.0f;
            const float m1i = b ? sTi[k][n + 1] : 0.0f;
            float t0 = u0r * m0r - u0i * m0i; u0i = u0r * m0i + u0i * m0r; u0r = t0;
            float t1 = u1r * m1r - u1i * m1i; u1i = u1r * m1i + u1i * m1r; u1r = t1;
        }
        const float w0r = sWr[n],     w0i = sWi[n];
        const float w1r = sWr[n + 1], w1i = sWi[n + 1];
        #pragma unroll
        for (int j = 0; j < LCH; ++j) {
            acc[j] += u0r + u1r;
            float t0 = u0r * w0r - u0i * w0i; u0i = u0r * w0i + u0i * w0r; u0r = t0;
            float t1 = u1r * w1r - u1i * w1i; u1i = u1r * w1i + u1i * w1r; u1r = t1;
        }
    }

    float* op = out + (size_t)h * L_DIM + t * LCH;
    #pragma unroll
    for (int j = 0; j < LCH; j += 4) {
        *reinterpret_cast<float4*>(op + j) =
            make_float4(acc[j], acc[j + 1], acc[j + 2], acc[j + 3]);
    }
}

extern "C" void kernel_launch(void* const* d_in, const int* in_sizes, int n_in,
                              void* d_out, int out_size, void* d_ws, size_t ws_size,
                              hipStream_t stream) {
    const float* log_dt     = (const float*)d_in[0];
    const float* B_ri       = (const float*)d_in[1];
    const float* inv_A_real = (const float*)d_in[2];
    const float* A_imag     = (const float*)d_in[3];
    const float* C_ri       = (const float*)d_in[4];
    float* out = (float*)d_out;
    hipLaunchKernelGGL(s4d_gen_kernel, dim3(H_DIM), dim3(TPB), 0, stream,
                       log_dt, B_ri, inv_A_real, A_imag, C_ri, out);
}